// Round 5
// baseline (870.006 us; speedup 1.0000x reference)
//
#include <hip/hip_runtime.h>
#include <hip/hip_fp16.h>
#include <cmath>

// Problem constants
constexpr int B_ = 64, N_ = 50000, L_ = 8, E_ = 100000, U_ = 20000, G_ = 20000, R_ = 64, D_ = 16, C_ = 2;
constexpr int EPL_ = E_ + 3 * U_ + 4;  // padded edge slots per layer (+4 sentinel tail)
constexpr int BC = 64;                 // whole batch in one chunk
constexpr int F = BC * 2;              // float4 chunks per node row (2 KB, fp16)

// h fp16 layout: h[node][b][d], d-contiguous. chunk f = b*2 + dh (dh covers d = dh*8..dh*8+7).
// Node N_ is a reserved all-zero row (padding target).

__device__ __forceinline__ float tanh_fast(float x) {
  float e = __expf(2.0f * x);                       // v_exp_f32 path
  return 1.0f - 2.0f * __builtin_amdgcn_rcpf(e + 1.0f);  // v_rcp_f32
}

// ---------------- CSR build (batch-independent, counts padded to mult of 4) --

__global__ __launch_bounds__(256) void hist_kernel(
    const int* __restrict__ dst_pos, int* __restrict__ cnt) {
  int e = blockIdx.x * 256 + threadIdx.x;
  int li = blockIdx.y;
  if (e >= E_) return;
  atomicAdd(&cnt[li * U_ + dst_pos[li * E_ + e]], 1);
}

__global__ __launch_bounds__(1024) void scan_kernel(
    const int* __restrict__ cnt, int* __restrict__ offs, int* __restrict__ cursor) {
  __shared__ int sd[1024];
  int li = blockIdx.x;
  int tid = threadIdx.x;
  int carry = 0;
  for (int base = 0; base < U_; base += 1024) {
    int i = base + tid;
    int c = (i < U_) ? cnt[li * U_ + i] : 0;
    int v = (c + 3) & ~3;
    sd[tid] = v;
    __syncthreads();
    for (int off = 1; off < 1024; off <<= 1) {
      int t = (tid >= off) ? sd[tid - off] : 0;
      __syncthreads();
      sd[tid] += t;
      __syncthreads();
    }
    int excl = sd[tid] - v;
    if (i < U_) {
      offs[li * (U_ + 1) + i] = carry + excl;
      cursor[li * U_ + i] = carry + excl;
    }
    int total = sd[1023];
    __syncthreads();
    carry += total;
  }
  if (tid == 0) offs[li * (U_ + 1) + U_] = carry;
}

__global__ __launch_bounds__(256) void scatter_kernel(
    const int* __restrict__ dst_pos, const int* __restrict__ src,
    int* __restrict__ cursor, int* __restrict__ ssrc) {
  int e = blockIdx.x * 256 + threadIdx.x;
  int li = blockIdx.y;
  if (e >= E_) return;
  int u = dst_pos[li * E_ + e];
  int p = atomicAdd(&cursor[li * U_ + u], 1);
  ssrc[(size_t)li * EPL_ + p] = src[li * E_ + e];
}

__global__ __launch_bounds__(256) void pad_fill_k(
    const int* __restrict__ cursor, const int* __restrict__ offs,
    int* __restrict__ ssrc) {
  int t = blockIdx.x * 256 + threadIdx.x;
  if (t >= L_ * U_) return;
  int li = t / U_, u = t % U_;
  int end = cursor[li * U_ + u];
  int pend = offs[li * (U_ + 1) + u + 1];
  int* sp = ssrc + (size_t)li * EPL_;
  for (int p = end; p < pend; ++p) sp[p] = N_;
  if (u == U_ - 1) {  // sentinel tail so prefetch never reads junk
    int ptot = offs[li * (U_ + 1) + U_];
    for (int p = ptot; p < ptot + 4; ++p) sp[p] = N_;
  }
}

// ---------------- Compute ----------------

__global__ __launch_bounds__(256) void gene_init_k(
    const float* __restrict__ X, const float* __restrict__ w_in,
    const float* __restrict__ b_in, const int* __restrict__ gene_map,
    float4* __restrict__ h4) {
  int t = blockIdx.x * 256 + threadIdx.x;
  if (t >= G_ * BC) return;
  int b = t % BC;
  int g = t / BC;
  float x = X[b * G_ + g];
  int node = gene_map[g];
  float4 out[2];
  __half2* oh = reinterpret_cast<__half2*>(out);
#pragma unroll
  for (int k = 0; k < 8; ++k) {
    float r0 = fmaf(x, w_in[2 * k], b_in[2 * k]);
    float r1 = fmaf(x, w_in[2 * k + 1], b_in[2 * k + 1]);
    oh[k] = __float22half2_rn(make_float2(r0, r1));
  }
  h4[(size_t)node * F + b * 2] = out[0];
  h4[(size_t)node * F + b * 2 + 1] = out[1];
}

// Pure gather-sum: each wave owns 4 consecutive u's = one contiguous padded
// edge range. fp16 packed accumulation, flush = single store per r. No LDS,
// no __syncthreads.
__global__ __launch_bounds__(256) void gather_k(
    const float4* __restrict__ h4, const int* __restrict__ offs,
    const int* __restrict__ ssrc, float4* __restrict__ agg4, int li) {
  int tid = threadIdx.x;
  int wave = tid >> 6, lane = tid & 63;
  int w = blockIdx.x * 4 + wave;
  int u0 = w * 4;
  const int* ob = offs + li * (U_ + 1) + u0;
  int offv[5];
#pragma unroll
  for (int i = 0; i < 5; ++i) offv[i] = ob[i];
  const int* sp = ssrc + (size_t)li * EPL_;

  __half2 acc[4][2][4];
  const __half2 z = __half2half2(__float2half(0.f));
#pragma unroll
  for (int j = 0; j < 4; ++j)
#pragma unroll
    for (int r = 0; r < 2; ++r)
#pragma unroll
      for (int k = 0; k < 4; ++k) acc[j][r][k] = z;

  auto flushu = [&](int u) {
#pragma unroll
    for (int r = 0; r < 2; ++r) {
      float4 outv;
      __half2* ov = reinterpret_cast<__half2*>(&outv);
#pragma unroll
      for (int k = 0; k < 4; ++k) {
        float2 f0 = __half22float2(acc[0][r][k]);
        float2 f1 = __half22float2(acc[1][r][k]);
        float2 f2 = __half22float2(acc[2][r][k]);
        float2 f3 = __half22float2(acc[3][r][k]);
        ov[k] = __float22half2_rn(make_float2((f0.x + f1.x) + (f2.x + f3.x),
                                              (f0.y + f1.y) + (f2.y + f3.y)));
      }
      agg4[(size_t)u * F + lane + r * 64] = outv;
    }
#pragma unroll
    for (int j = 0; j < 4; ++j)
#pragma unroll
      for (int r = 0; r < 2; ++r)
#pragma unroll
        for (int k = 0; k < 4; ++k) acc[j][r][k] = z;
  };

  int e = offv[0];
  int eend = offv[4];
  int uj = 0;
  while (uj < 4 && offv[uj + 1] == e) { flushu(u0 + uj); ++uj; }

  int4 id = *(const int4*)(sp + e);  // sentinel tail makes this always safe
  while (e < eend) {
    int4 idn = *(const int4*)(sp + e + 4);
    float4 v[4][2];
    v[0][0] = h4[(size_t)id.x * F + lane]; v[0][1] = h4[(size_t)id.x * F + lane + 64];
    v[1][0] = h4[(size_t)id.y * F + lane]; v[1][1] = h4[(size_t)id.y * F + lane + 64];
    v[2][0] = h4[(size_t)id.z * F + lane]; v[2][1] = h4[(size_t)id.z * F + lane + 64];
    v[3][0] = h4[(size_t)id.w * F + lane]; v[3][1] = h4[(size_t)id.w * F + lane + 64];
#pragma unroll
    for (int j = 0; j < 4; ++j)
#pragma unroll
      for (int r = 0; r < 2; ++r) {
        const __half2* p = reinterpret_cast<const __half2*>(&v[j][r]);
#pragma unroll
        for (int k = 0; k < 4; ++k) acc[j][r][k] = __hadd2(acc[j][r][k], p[k]);
      }
    e += 4;
    if (e == offv[uj + 1]) {
      flushu(u0 + uj); ++uj;
      while (uj < 4 && offv[uj + 1] == e) { flushu(u0 + uj); ++uj; }
    }
    id = idn;
  }
}

// Dense epilogue: sums (fp16) -> @W + bias + tanh -> h[dst_unique] (fp16).
// 2 u's per 256-block; partner half of the d-vector via shfl_xor(1).
__global__ __launch_bounds__(256) void dense_k(
    const float4* __restrict__ agg4, const float* __restrict__ W,
    const float* __restrict__ bias, const int* __restrict__ dst_unique,
    float4* __restrict__ h4, int li) {
  __shared__ float Wlds[256];
  int tid = threadIdx.x;
  Wlds[tid] = W[li * 256 + tid];
  __syncthreads();
  int ul = tid >> 7, f = tid & 127;
  int u = blockIdx.x * 2 + ul;
  int dh = f & 1;
  float4 mine = agg4[(size_t)u * F + f];
  float4 other;
  other.x = __shfl_xor(mine.x, 1, 64);
  other.y = __shfl_xor(mine.y, 1, 64);
  other.z = __shfl_xor(mine.z, 1, 64);
  other.w = __shfl_xor(mine.w, 1, 64);
  float a[16];
  const __half2* mh = reinterpret_cast<const __half2*>(&mine);
  const __half2* oh = reinterpret_cast<const __half2*>(&other);
#pragma unroll
  for (int k = 0; k < 4; ++k) {
    float2 fm = __half22float2(mh[k]);
    float2 fo = __half22float2(oh[k]);
    a[dh * 8 + 2 * k] = fm.x; a[dh * 8 + 2 * k + 1] = fm.y;
    a[(1 - dh) * 8 + 2 * k] = fo.x; a[(1 - dh) * 8 + 2 * k + 1] = fo.y;
  }
  float m[8];
#pragma unroll
  for (int j = 0; j < 8; ++j) m[j] = 0.f;
#pragma unroll
  for (int d = 0; d < 16; ++d) {
    float s = a[d];
    const float4* wr = (const float4*)&Wlds[d * 16 + dh * 8];
    float4 w0 = wr[0], w1 = wr[1];
    m[0] = fmaf(s, w0.x, m[0]); m[1] = fmaf(s, w0.y, m[1]);
    m[2] = fmaf(s, w0.z, m[2]); m[3] = fmaf(s, w0.w, m[3]);
    m[4] = fmaf(s, w1.x, m[4]); m[5] = fmaf(s, w1.y, m[5]);
    m[6] = fmaf(s, w1.z, m[6]); m[7] = fmaf(s, w1.w, m[7]);
  }
  int node = dst_unique[li * U_ + u];
  const float4* bp = (const float4*)(bias + (size_t)node * 16 + dh * 8);
  float4 b0 = bp[0], b1 = bp[1];
  float bb[8] = {b0.x, b0.y, b0.z, b0.w, b1.x, b1.y, b1.z, b1.w};
  float4 outv;
  __half2* ov = reinterpret_cast<__half2*>(&outv);
#pragma unroll
  for (int k = 0; k < 4; ++k) {
    float t0 = tanh_fast(m[2 * k] + bb[2 * k]);
    float t1 = tanh_fast(m[2 * k + 1] + bb[2 * k + 1]);
    ov[k] = __float22half2_rn(make_float2(t0, t1));
  }
  h4[(size_t)node * F + f] = outv;
}

__global__ __launch_bounds__(64) void head_k(
    const float4* __restrict__ h4, const float* __restrict__ W_head,
    const float* __restrict__ b_head, const int* __restrict__ root_ids,
    float* __restrict__ out) {
  int bl = blockIdx.x;
  int r = threadIdx.x;
  int node = root_ids[r];
  float4 p0 = h4[(size_t)node * F + bl * 2];
  float4 p1 = h4[(size_t)node * F + bl * 2 + 1];
  float v[16];
  const __half2* ph0 = reinterpret_cast<const __half2*>(&p0);
  const __half2* ph1 = reinterpret_cast<const __half2*>(&p1);
#pragma unroll
  for (int k = 0; k < 4; ++k) {
    float2 f0 = __half22float2(ph0[k]);
    float2 f1 = __half22float2(ph1[k]);
    v[2 * k] = f0.x; v[2 * k + 1] = f0.y;
    v[8 + 2 * k] = f1.x; v[8 + 2 * k + 1] = f1.y;
  }
  float acc0 = 0.f, acc1 = 0.f;
#pragma unroll
  for (int d = 0; d < 16; ++d) {
    acc0 = fmaf(v[d], W_head[r * 16 + d], acc0);
    acc1 = fmaf(v[d], W_head[1024 + r * 16 + d], acc1);
  }
  for (int off = 32; off; off >>= 1) {
    acc0 += __shfl_down(acc0, off, 64);
    acc1 += __shfl_down(acc1, off, 64);
  }
  if (r == 0) {
    out[bl * 2 + 0] = acc0 + b_head[0];
    out[bl * 2 + 1] = acc1 + b_head[1];
  }
}

__global__ void zero_out_k(float* out, int n) {
  int t = blockIdx.x * 256 + threadIdx.x;
  if (t < n) out[t] = 0.f;
}

// ---------------- Host side ----------------

static size_t need_bytes() {
  return (size_t)(N_ + 1) * F * 16 + (size_t)U_ * F * 16 +
         (size_t)L_ * U_ * 4 * 2 + (size_t)L_ * (U_ + 1) * 4 +
         (size_t)L_ * EPL_ * 4;
}

extern "C" void kernel_launch(void* const* d_in, const int* in_sizes, int n_in,
                              void* d_out, int out_size, void* d_ws, size_t ws_size,
                              hipStream_t stream) {
  if (ws_size < need_bytes()) {
    zero_out_k<<<(out_size + 255) / 256, 256, 0, stream>>>((float*)d_out, out_size);
    return;
  }
  const float* X = (const float*)d_in[0];
  const float* w_in = (const float*)d_in[1];
  const float* b_in = (const float*)d_in[2];
  const float* W = (const float*)d_in[3];
  const float* bias = (const float*)d_in[4];
  const float* W_head = (const float*)d_in[5];
  const float* b_head = (const float*)d_in[6];
  const int* gene_map = (const int*)d_in[7];
  const int* src = (const int*)d_in[8];
  const int* dst_pos = (const int*)d_in[9];
  const int* dst_unique = (const int*)d_in[10];
  const int* root_ids = (const int*)d_in[11];
  float* out = (float*)d_out;

  const size_t h_bytes = (size_t)(N_ + 1) * F * 16;   // + zero sentinel row
  const size_t agg_bytes = (size_t)U_ * F * 16;
  const size_t cnt_bytes = (size_t)L_ * U_ * 4;
  const size_t offs_bytes = (size_t)L_ * (U_ + 1) * 4;
  const size_t cur_bytes = (size_t)L_ * U_ * 4;

  char* ws = (char*)d_ws;
  float4* h4 = (float4*)ws;
  float4* agg4 = (float4*)(ws + h_bytes);
  int* cnt = (int*)(ws + h_bytes + agg_bytes);
  int* offs = (int*)(ws + h_bytes + agg_bytes + cnt_bytes);
  int* cursor = (int*)(ws + h_bytes + agg_bytes + cnt_bytes + offs_bytes);
  int* ssrc = (int*)(ws + h_bytes + agg_bytes + cnt_bytes + offs_bytes + cur_bytes);

  hipMemsetAsync(cnt, 0, cnt_bytes, stream);
  hipMemsetAsync(h4, 0, h_bytes, stream);
  dim3 egrid((E_ + 255) / 256, L_);
  hist_kernel<<<egrid, 256, 0, stream>>>(dst_pos, cnt);
  scan_kernel<<<L_, 1024, 0, stream>>>(cnt, offs, cursor);
  scatter_kernel<<<egrid, 256, 0, stream>>>(dst_pos, src, cursor, ssrc);
  pad_fill_k<<<(L_ * U_ + 255) / 256, 256, 0, stream>>>(cursor, offs, ssrc);

  gene_init_k<<<(G_ * BC + 255) / 256, 256, 0, stream>>>(X, w_in, b_in, gene_map, h4);

  const int gather_grid = U_ / 16;  // 4 waves/block, 4 u's per wave
  const int dense_grid = U_ / 2;
  for (int li = 0; li < L_; ++li) {
    gather_k<<<gather_grid, 256, 0, stream>>>(h4, offs, ssrc, agg4, li);
    dense_k<<<dense_grid, 256, 0, stream>>>(agg4, W, bias, dst_unique, h4, li);
  }

  head_k<<<BC, 64, 0, stream>>>(h4, W_head, b_head, root_ids, out);
}

// Round 6
// 724.093 us; speedup vs baseline: 1.2015x; 1.2015x over previous
//
#include <hip/hip_runtime.h>
#include <hip/hip_fp16.h>
#include <cmath>

// Problem constants
constexpr int B_ = 64, N_ = 50000, L_ = 8, E_ = 100000, U_ = 20000, G_ = 20000, R_ = 64, D_ = 16, C_ = 2;
constexpr int EPL_ = E_ + 3 * U_ + 8;  // padded edge slots per layer (+8 sentinel tail)
constexpr int BC = 64;                 // whole batch in one chunk
constexpr int F = BC * 2;              // float4 chunks per node row (2 KB, fp16)

// h fp16 layout: h[node][b][d], d-contiguous. chunk f = b*2 + dh (dh covers d = dh*8..dh*8+7).
// Node N_ is a reserved all-zero row (padding target).

__device__ __forceinline__ float tanh_fast(float x) {
  float e = __expf(2.0f * x);
  return 1.0f - 2.0f * __builtin_amdgcn_rcpf(e + 1.0f);
}

// ---------------- CSR build (batch-independent, counts padded to mult of 4) --

__global__ __launch_bounds__(256) void hist_kernel(
    const int* __restrict__ dst_pos, int* __restrict__ cnt) {
  int e = blockIdx.x * 256 + threadIdx.x;
  int li = blockIdx.y;
  if (e >= E_) return;
  atomicAdd(&cnt[li * U_ + dst_pos[li * E_ + e]], 1);
}

__global__ __launch_bounds__(1024) void scan_kernel(
    const int* __restrict__ cnt, int* __restrict__ offs, int* __restrict__ cursor) {
  __shared__ int sd[1024];
  int li = blockIdx.x;
  int tid = threadIdx.x;
  int carry = 0;
  for (int base = 0; base < U_; base += 1024) {
    int i = base + tid;
    int c = (i < U_) ? cnt[li * U_ + i] : 0;
    int v = (c + 3) & ~3;
    sd[tid] = v;
    __syncthreads();
    for (int off = 1; off < 1024; off <<= 1) {
      int t = (tid >= off) ? sd[tid - off] : 0;
      __syncthreads();
      sd[tid] += t;
      __syncthreads();
    }
    int excl = sd[tid] - v;
    if (i < U_) {
      offs[li * (U_ + 1) + i] = carry + excl;
      cursor[li * U_ + i] = carry + excl;
    }
    int total = sd[1023];
    __syncthreads();
    carry += total;
  }
  if (tid == 0) offs[li * (U_ + 1) + U_] = carry;
}

__global__ __launch_bounds__(256) void scatter_kernel(
    const int* __restrict__ dst_pos, const int* __restrict__ src,
    int* __restrict__ cursor, int* __restrict__ ssrc) {
  int e = blockIdx.x * 256 + threadIdx.x;
  int li = blockIdx.y;
  if (e >= E_) return;
  int u = dst_pos[li * E_ + e];
  int p = atomicAdd(&cursor[li * U_ + u], 1);
  ssrc[(size_t)li * EPL_ + p] = src[li * E_ + e];
}

__global__ __launch_bounds__(256) void pad_fill_k(
    const int* __restrict__ cursor, const int* __restrict__ offs,
    int* __restrict__ ssrc) {
  int t = blockIdx.x * 256 + threadIdx.x;
  if (t >= L_ * U_) return;
  int li = t / U_, u = t % U_;
  int end = cursor[li * U_ + u];
  int pend = offs[li * (U_ + 1) + u + 1];
  int* sp = ssrc + (size_t)li * EPL_;
  for (int p = end; p < pend; ++p) sp[p] = N_;
  if (u == U_ - 1) {  // 8-int sentinel tail so 2-deep prefetch never reads junk
    int ptot = offs[li * (U_ + 1) + U_];
    for (int p = ptot; p < ptot + 8; ++p) sp[p] = N_;
  }
}

// ---------------- Compute ----------------

__global__ __launch_bounds__(256) void gene_init_k(
    const float* __restrict__ X, const float* __restrict__ w_in,
    const float* __restrict__ b_in, const int* __restrict__ gene_map,
    float4* __restrict__ h4) {
  int t = blockIdx.x * 256 + threadIdx.x;
  if (t >= G_ * BC) return;
  int b = t % BC;
  int g = t / BC;
  float x = X[b * G_ + g];
  int node = gene_map[g];
  float4 out[2];
  __half2* oh = reinterpret_cast<__half2*>(out);
#pragma unroll
  for (int k = 0; k < 8; ++k) {
    float r0 = fmaf(x, w_in[2 * k], b_in[2 * k]);
    float r1 = fmaf(x, w_in[2 * k + 1], b_in[2 * k + 1]);
    oh[k] = __float22half2_rn(make_float2(r0, r1));
  }
  h4[(size_t)node * F + b * 2] = out[0];
  h4[(size_t)node * F + b * 2 + 1] = out[1];
}

// Pure gather-sum: each wave owns 4 consecutive u's = one contiguous padded
// edge range. Ping-pong row buffers (2-deep pipeline), indices 2 groups ahead.
__global__ __launch_bounds__(256) void gather_k(
    const float4* __restrict__ h4, const int* __restrict__ offs,
    const int* __restrict__ ssrc, float4* __restrict__ agg4, int li) {
  int tid = threadIdx.x;
  int wave = tid >> 6, lane = tid & 63;
  int w = blockIdx.x * 4 + wave;
  int u0 = w * 4;
  const int* ob = offs + li * (U_ + 1) + u0;
  int offv[5];
#pragma unroll
  for (int i = 0; i < 5; ++i) offv[i] = ob[i];
  const int* sp = ssrc + (size_t)li * EPL_;

  __half2 acc[4][2][4];
  const __half2 z = __half2half2(__float2half(0.f));
#pragma unroll
  for (int j = 0; j < 4; ++j)
#pragma unroll
    for (int r = 0; r < 2; ++r)
#pragma unroll
      for (int k = 0; k < 4; ++k) acc[j][r][k] = z;

  auto flushu = [&](int u) {
#pragma unroll
    for (int r = 0; r < 2; ++r) {
      float4 outv;
      __half2* ov = reinterpret_cast<__half2*>(&outv);
#pragma unroll
      for (int k = 0; k < 4; ++k) {
        float2 f0 = __half22float2(acc[0][r][k]);
        float2 f1 = __half22float2(acc[1][r][k]);
        float2 f2 = __half22float2(acc[2][r][k]);
        float2 f3 = __half22float2(acc[3][r][k]);
        ov[k] = __float22half2_rn(make_float2((f0.x + f1.x) + (f2.x + f3.x),
                                              (f0.y + f1.y) + (f2.y + f3.y)));
      }
      agg4[(size_t)u * F + lane + r * 64] = outv;
    }
#pragma unroll
    for (int j = 0; j < 4; ++j)
#pragma unroll
      for (int r = 0; r < 2; ++r)
#pragma unroll
        for (int k = 0; k < 4; ++k) acc[j][r][k] = z;
  };

  auto loadRows = [&](float4 (&v)[4][2], int4 id) {
    v[0][0] = h4[(size_t)id.x * F + lane]; v[0][1] = h4[(size_t)id.x * F + lane + 64];
    v[1][0] = h4[(size_t)id.y * F + lane]; v[1][1] = h4[(size_t)id.y * F + lane + 64];
    v[2][0] = h4[(size_t)id.z * F + lane]; v[2][1] = h4[(size_t)id.z * F + lane + 64];
    v[3][0] = h4[(size_t)id.w * F + lane]; v[3][1] = h4[(size_t)id.w * F + lane + 64];
  };
  auto accum = [&](const float4 (&v)[4][2]) {
#pragma unroll
    for (int j = 0; j < 4; ++j)
#pragma unroll
      for (int r = 0; r < 2; ++r) {
        const __half2* p = reinterpret_cast<const __half2*>(&v[j][r]);
#pragma unroll
        for (int k = 0; k < 4; ++k) acc[j][r][k] = __hadd2(acc[j][r][k], p[k]);
      }
  };

  int e = offv[0];
  int eend = offv[4];
  int uj = 0;
  while (uj < 4 && offv[uj + 1] == e) { flushu(u0 + uj); ++uj; }
  if (e >= eend) return;

  float4 va[4][2], vb[4][2];
  int4 idC = *(const int4*)(sp + e);      // ids for group e
  int4 idN = *(const int4*)(sp + e + 4);  // ids for group e+4 (sentinel/next-wave safe)
  loadRows(va, idC);

  for (;;) {
    // half 1: consume va (group e), prefetch rows of group e+4 into vb
    loadRows(vb, idN);
    idN = *(const int4*)(sp + e + 8);
    accum(va);
    e += 4;
    if (e == offv[uj + 1]) {
      flushu(u0 + uj); ++uj;
      while (uj < 4 && offv[uj + 1] == e) { flushu(u0 + uj); ++uj; }
    }
    if (e >= eend) break;
    // half 2: consume vb, prefetch into va
    loadRows(va, idN);
    idN = *(const int4*)(sp + e + 8);
    accum(vb);
    e += 4;
    if (e == offv[uj + 1]) {
      flushu(u0 + uj); ++uj;
      while (uj < 4 && offv[uj + 1] == e) { flushu(u0 + uj); ++uj; }
    }
    if (e >= eend) break;
  }
}

// Dense epilogue: one thread per (u,b). All-static indexing (no scratch).
// sums (fp16) -> @W + bias + tanh -> h[dst_unique] (fp16).
__global__ __launch_bounds__(256) void dense_k(
    const float4* __restrict__ agg4, const float* __restrict__ W,
    const float* __restrict__ bias, const int* __restrict__ dst_unique,
    float4* __restrict__ h4, int li) {
  __shared__ float Wlds[256];
  int tid = threadIdx.x;
  Wlds[tid] = W[li * 256 + tid];
  __syncthreads();
  int t = blockIdx.x * 256 + tid;
  int u = t >> 6, b = t & 63;
  float4 c0 = agg4[(size_t)u * F + b * 2];
  float4 c1 = agg4[(size_t)u * F + b * 2 + 1];
  float a[16];
  {
    const __half2* p0 = reinterpret_cast<const __half2*>(&c0);
    const __half2* p1 = reinterpret_cast<const __half2*>(&c1);
#pragma unroll
    for (int k = 0; k < 4; ++k) {
      float2 f0 = __half22float2(p0[k]);
      float2 f1 = __half22float2(p1[k]);
      a[2 * k] = f0.x; a[2 * k + 1] = f0.y;
      a[8 + 2 * k] = f1.x; a[8 + 2 * k + 1] = f1.y;
    }
  }
  float m[16];
#pragma unroll
  for (int j = 0; j < 16; ++j) m[j] = 0.f;
#pragma unroll
  for (int d = 0; d < 16; ++d) {
    float s = a[d];
    const float4* wr = (const float4*)&Wlds[d * 16];  // broadcast reads (free)
    float4 w0 = wr[0], w1 = wr[1], w2 = wr[2], w3 = wr[3];
    m[0] = fmaf(s, w0.x, m[0]);  m[1] = fmaf(s, w0.y, m[1]);
    m[2] = fmaf(s, w0.z, m[2]);  m[3] = fmaf(s, w0.w, m[3]);
    m[4] = fmaf(s, w1.x, m[4]);  m[5] = fmaf(s, w1.y, m[5]);
    m[6] = fmaf(s, w1.z, m[6]);  m[7] = fmaf(s, w1.w, m[7]);
    m[8] = fmaf(s, w2.x, m[8]);  m[9] = fmaf(s, w2.y, m[9]);
    m[10] = fmaf(s, w2.z, m[10]); m[11] = fmaf(s, w2.w, m[11]);
    m[12] = fmaf(s, w3.x, m[12]); m[13] = fmaf(s, w3.y, m[13]);
    m[14] = fmaf(s, w3.z, m[14]); m[15] = fmaf(s, w3.w, m[15]);
  }
  int node = dst_unique[li * U_ + u];  // wave-uniform
  const float4* bp = (const float4*)(bias + (size_t)node * 16);
  float4 b0 = bp[0], b1 = bp[1], b2 = bp[2], b3 = bp[3];
  float bb[16] = {b0.x, b0.y, b0.z, b0.w, b1.x, b1.y, b1.z, b1.w,
                  b2.x, b2.y, b2.z, b2.w, b3.x, b3.y, b3.z, b3.w};
  float4 o0, o1;
  __half2* ov0 = reinterpret_cast<__half2*>(&o0);
  __half2* ov1 = reinterpret_cast<__half2*>(&o1);
#pragma unroll
  for (int k = 0; k < 4; ++k) {
    ov0[k] = __float22half2_rn(make_float2(tanh_fast(m[2 * k] + bb[2 * k]),
                                           tanh_fast(m[2 * k + 1] + bb[2 * k + 1])));
    ov1[k] = __float22half2_rn(make_float2(tanh_fast(m[8 + 2 * k] + bb[8 + 2 * k]),
                                           tanh_fast(m[8 + 2 * k + 1] + bb[8 + 2 * k + 1])));
  }
  h4[(size_t)node * F + b * 2] = o0;
  h4[(size_t)node * F + b * 2 + 1] = o1;
}

__global__ __launch_bounds__(64) void head_k(
    const float4* __restrict__ h4, const float* __restrict__ W_head,
    const float* __restrict__ b_head, const int* __restrict__ root_ids,
    float* __restrict__ out) {
  int bl = blockIdx.x;
  int r = threadIdx.x;
  int node = root_ids[r];
  float4 p0 = h4[(size_t)node * F + bl * 2];
  float4 p1 = h4[(size_t)node * F + bl * 2 + 1];
  float v[16];
  const __half2* ph0 = reinterpret_cast<const __half2*>(&p0);
  const __half2* ph1 = reinterpret_cast<const __half2*>(&p1);
#pragma unroll
  for (int k = 0; k < 4; ++k) {
    float2 f0 = __half22float2(ph0[k]);
    float2 f1 = __half22float2(ph1[k]);
    v[2 * k] = f0.x; v[2 * k + 1] = f0.y;
    v[8 + 2 * k] = f1.x; v[8 + 2 * k + 1] = f1.y;
  }
  float acc0 = 0.f, acc1 = 0.f;
#pragma unroll
  for (int d = 0; d < 16; ++d) {
    acc0 = fmaf(v[d], W_head[r * 16 + d], acc0);
    acc1 = fmaf(v[d], W_head[1024 + r * 16 + d], acc1);
  }
  for (int off = 32; off; off >>= 1) {
    acc0 += __shfl_down(acc0, off, 64);
    acc1 += __shfl_down(acc1, off, 64);
  }
  if (r == 0) {
    out[bl * 2 + 0] = acc0 + b_head[0];
    out[bl * 2 + 1] = acc1 + b_head[1];
  }
}

__global__ void zero_out_k(float* out, int n) {
  int t = blockIdx.x * 256 + threadIdx.x;
  if (t < n) out[t] = 0.f;
}

// ---------------- Host side ----------------

static size_t need_bytes() {
  return (size_t)(N_ + 1) * F * 16 + (size_t)U_ * F * 16 +
         (size_t)L_ * U_ * 4 * 2 + (size_t)L_ * (U_ + 1) * 4 +
         (size_t)L_ * EPL_ * 4;
}

extern "C" void kernel_launch(void* const* d_in, const int* in_sizes, int n_in,
                              void* d_out, int out_size, void* d_ws, size_t ws_size,
                              hipStream_t stream) {
  if (ws_size < need_bytes()) {
    zero_out_k<<<(out_size + 255) / 256, 256, 0, stream>>>((float*)d_out, out_size);
    return;
  }
  const float* X = (const float*)d_in[0];
  const float* w_in = (const float*)d_in[1];
  const float* b_in = (const float*)d_in[2];
  const float* W = (const float*)d_in[3];
  const float* bias = (const float*)d_in[4];
  const float* W_head = (const float*)d_in[5];
  const float* b_head = (const float*)d_in[6];
  const int* gene_map = (const int*)d_in[7];
  const int* src = (const int*)d_in[8];
  const int* dst_pos = (const int*)d_in[9];
  const int* dst_unique = (const int*)d_in[10];
  const int* root_ids = (const int*)d_in[11];
  float* out = (float*)d_out;

  const size_t h_bytes = (size_t)(N_ + 1) * F * 16;   // + zero sentinel row
  const size_t agg_bytes = (size_t)U_ * F * 16;
  const size_t cnt_bytes = (size_t)L_ * U_ * 4;
  const size_t offs_bytes = (size_t)L_ * (U_ + 1) * 4;
  const size_t cur_bytes = (size_t)L_ * U_ * 4;

  char* ws = (char*)d_ws;
  float4* h4 = (float4*)ws;
  float4* agg4 = (float4*)(ws + h_bytes);
  int* cnt = (int*)(ws + h_bytes + agg_bytes);
  int* offs = (int*)(ws + h_bytes + agg_bytes + cnt_bytes);
  int* cursor = (int*)(ws + h_bytes + agg_bytes + cnt_bytes + offs_bytes);
  int* ssrc = (int*)(ws + h_bytes + agg_bytes + cnt_bytes + offs_bytes + cur_bytes);

  hipMemsetAsync(cnt, 0, cnt_bytes, stream);
  hipMemsetAsync(h4, 0, h_bytes, stream);
  dim3 egrid((E_ + 255) / 256, L_);
  hist_kernel<<<egrid, 256, 0, stream>>>(dst_pos, cnt);
  scan_kernel<<<L_, 1024, 0, stream>>>(cnt, offs, cursor);
  scatter_kernel<<<egrid, 256, 0, stream>>>(dst_pos, src, cursor, ssrc);
  pad_fill_k<<<(L_ * U_ + 255) / 256, 256, 0, stream>>>(cursor, offs, ssrc);

  gene_init_k<<<(G_ * BC + 255) / 256, 256, 0, stream>>>(X, w_in, b_in, gene_map, h4);

  const int gather_grid = U_ / 16;  // 4 waves/block, 4 u's per wave
  const int dense_grid = U_ * BC / 256;
  for (int li = 0; li < L_; ++li) {
    gather_k<<<gather_grid, 256, 0, stream>>>(h4, offs, ssrc, agg4, li);
    dense_k<<<dense_grid, 256, 0, stream>>>(agg4, W, bias, dst_unique, h4, li);
  }

  head_k<<<BC, 64, 0, stream>>>(h4, W_head, b_head, root_ids, out);
}